// Round 2
// baseline (500.226 us; speedup 1.0000x reference)
//
#include <hip/hip_runtime.h>
#include <stdint.h>

#define N_TOK 4096
#define C_DIM 256

typedef __attribute__((ext_vector_type(8))) short short8;
typedef __attribute__((ext_vector_type(4))) float floatx4;

__device__ __forceinline__ unsigned short bf16_rne(float f) {
    union { float f; unsigned int u; } v; v.f = f;
    unsigned int u = v.u;
    unsigned int rounded = u + 0x7FFFu + ((u >> 16) & 1u);
    return (unsigned short)(rounded >> 16);
}
__device__ __forceinline__ float bf16_to_f(unsigned short h) {
    union { unsigned int u; float f; } v; v.u = ((unsigned int)h) << 16;
    return v.f;
}
// split f = hi + lo (both bf16) with combined error ~2^-18 relative
__device__ __forceinline__ void split_bf16(float f, unsigned short& h, unsigned short& l) {
    h = bf16_rne(f);
    l = bf16_rne(f - bf16_to_f(h));
}

// ---------------------------------------------------------------------------
// proj_kernel: Out[n,o] = sum_c x[b,c,n]*W[o,c] + bias[o] (+pos[o,n] for k)
// Split-bf16 3-term MFMA for ~fp32 accuracy. Outputs:
//   Qf[b][n][o] fp32, Kf[b][n][o] fp32 (K' = k + pos), Vg[b][o][n] bf16
// ---------------------------------------------------------------------------
__global__ __launch_bounds__(256) void proj_kernel(
    const float* __restrict__ x,
    const float* __restrict__ Wq, const float* __restrict__ bq,
    const float* __restrict__ Wk, const float* __restrict__ bk,
    const float* __restrict__ Wv, const float* __restrict__ bv,
    const float* __restrict__ relh, const float* __restrict__ relw,
    float* __restrict__ Qf,
    float* __restrict__ Kf,
    unsigned short* __restrict__ Vg)
{
    __shared__ unsigned short Xh[64 * 72];    // x tile hi [n_loc][c_loc]
    __shared__ unsigned short Xl[64 * 72];    // x tile lo
    __shared__ unsigned short Wh[256 * 72];   // W tile hi [o][c_loc]; reused for V transpose
    __shared__ unsigned short Wl[256 * 72];   // W tile lo

    const int t    = threadIdx.x;
    const int wave = t >> 6;
    const int lane = t & 63;
    const int l15  = lane & 15;
    const int quad = lane >> 4;

    const int bp   = blockIdx.x >> 6;       // 0..11
    const int proj = bp % 3;
    const int b    = bp / 3;
    const int n0   = (blockIdx.x & 63) * 64;

    const float* W    = (proj == 0) ? Wq : (proj == 1) ? Wk : Wv;
    const float* bias = (proj == 0) ? bq : (proj == 1) ? bk : bv;

    floatx4 acc[16];
#pragma unroll
    for (int i = 0; i < 16; i++) acc[i] = (floatx4){0.f, 0.f, 0.f, 0.f};

    for (int c0 = 0; c0 < 256; c0 += 64) {
        // ---- stage x tile transposed + split: Xh/Xl[n_loc][c_loc]
        {
            const int ch   = t & 15;     // float4 chunk along n
            const int crow = t >> 4;     // 0..15
#pragma unroll
            for (int pass = 0; pass < 4; pass++) {
                const int c_loc = pass * 16 + crow;
                const float4 xv = *(const float4*)(x + ((size_t)(b * C_DIM + c0 + c_loc)) * N_TOK + n0 + ch * 4);
                const int nb = ch * 4;
                unsigned short h, l;
                split_bf16(xv.x, h, l); Xh[(nb + 0) * 72 + c_loc] = h; Xl[(nb + 0) * 72 + c_loc] = l;
                split_bf16(xv.y, h, l); Xh[(nb + 1) * 72 + c_loc] = h; Xl[(nb + 1) * 72 + c_loc] = l;
                split_bf16(xv.z, h, l); Xh[(nb + 2) * 72 + c_loc] = h; Xl[(nb + 2) * 72 + c_loc] = l;
                split_bf16(xv.w, h, l); Xh[(nb + 3) * 72 + c_loc] = h; Xl[(nb + 3) * 72 + c_loc] = l;
            }
        }
        // ---- stage W tile split: Wh/Wl[o][c_loc]
        {
            const int ch   = t & 7;
            const int orow = t >> 3;     // 0..31
#pragma unroll
            for (int pass = 0; pass < 8; pass++) {
                const int o = pass * 32 + orow;
                const float* src = W + (size_t)o * 256 + c0 + ch * 8;
                const float4 w0 = *(const float4*)src;
                const float4 w1 = *(const float4*)(src + 4);
                short8 wh, wl;
                unsigned short h, l;
                split_bf16(w0.x, h, l); wh[0] = (short)h; wl[0] = (short)l;
                split_bf16(w0.y, h, l); wh[1] = (short)h; wl[1] = (short)l;
                split_bf16(w0.z, h, l); wh[2] = (short)h; wl[2] = (short)l;
                split_bf16(w0.w, h, l); wh[3] = (short)h; wl[3] = (short)l;
                split_bf16(w1.x, h, l); wh[4] = (short)h; wl[4] = (short)l;
                split_bf16(w1.y, h, l); wh[5] = (short)h; wl[5] = (short)l;
                split_bf16(w1.z, h, l); wh[6] = (short)h; wl[6] = (short)l;
                split_bf16(w1.w, h, l); wh[7] = (short)h; wl[7] = (short)l;
                *(short8*)&Wh[o * 72 + ch * 8] = wh;
                *(short8*)&Wl[o * 72 + ch * 8] = wl;
            }
        }
        __syncthreads();

        const int arow = (wave * 16 + l15) * 72 + quad * 8;
        const short8 a0h = *(const short8*)&Xh[arow];
        const short8 a0l = *(const short8*)&Xl[arow];
        const short8 a1h = *(const short8*)&Xh[arow + 32];
        const short8 a1l = *(const short8*)&Xl[arow + 32];
#pragma unroll
        for (int ot = 0; ot < 16; ot++) {
            const int brow = (ot * 16 + l15) * 72 + quad * 8;
            const short8 b0h = *(const short8*)&Wh[brow];
            const short8 b0l = *(const short8*)&Wl[brow];
            const short8 b1h = *(const short8*)&Wh[brow + 32];
            const short8 b1l = *(const short8*)&Wl[brow + 32];
            acc[ot] = __builtin_amdgcn_mfma_f32_16x16x32_bf16(a0h, b0h, acc[ot], 0, 0, 0);
            acc[ot] = __builtin_amdgcn_mfma_f32_16x16x32_bf16(a0l, b0h, acc[ot], 0, 0, 0);
            acc[ot] = __builtin_amdgcn_mfma_f32_16x16x32_bf16(a0h, b0l, acc[ot], 0, 0, 0);
            acc[ot] = __builtin_amdgcn_mfma_f32_16x16x32_bf16(a1h, b1h, acc[ot], 0, 0, 0);
            acc[ot] = __builtin_amdgcn_mfma_f32_16x16x32_bf16(a1l, b1h, acc[ot], 0, 0, 0);
            acc[ot] = __builtin_amdgcn_mfma_f32_16x16x32_bf16(a1h, b1l, acc[ot], 0, 0, 0);
        }
        __syncthreads();
    }

    // ---- epilogue ----
    const int h0 = n0 >> 6;   // pos column-block index: pos[c][n] = relh[c][n>>6] + relw[c][n&63]
    if (proj < 2) {
        float* Og = ((proj == 0) ? Qf : Kf) + ((size_t)b * N_TOK + n0) * C_DIM;
#pragma unroll
        for (int ot = 0; ot < 16; ot++) {
            const int o = ot * 16 + l15;
            const float bs = bias[o];
            float ph = 0.f;
            if (proj == 1) ph = relh[o * 64 + h0];
#pragma unroll
            for (int r = 0; r < 4; r++) {
                const int nl = wave * 16 + quad * 4 + r;
                float val = acc[ot][r] + bs;
                if (proj == 1) val += ph + relw[o * 64 + nl];
                Og[(size_t)nl * C_DIM + o] = val;
            }
        }
    } else {
        // V: bf16, transpose via LDS (reuse Wh) -> Vg[b][o][n]
#pragma unroll
        for (int ot = 0; ot < 16; ot++) {
            const int o = ot * 16 + l15;
            const float bs = bias[o];
            const unsigned int u0 = (unsigned int)bf16_rne(acc[ot][0] + bs) |
                                    ((unsigned int)bf16_rne(acc[ot][1] + bs) << 16);
            const unsigned int u1 = (unsigned int)bf16_rne(acc[ot][2] + bs) |
                                    ((unsigned int)bf16_rne(acc[ot][3] + bs) << 16);
            uint2 uv; uv.x = u0; uv.y = u1;
            *(uint2*)&Wh[o * 72 + wave * 16 + quad * 4] = uv;
        }
        __syncthreads();
        const int ch   = t & 7;
        const int orow = t >> 3;
#pragma unroll
        for (int pass = 0; pass < 8; pass++) {
            const int o = pass * 32 + orow;
            const short8 vv = *(const short8*)&Wh[o * 72 + ch * 8];
            *(short8*)&Vg[((size_t)b * C_DIM + o) * N_TOK + n0 + ch * 8] = vv;
        }
    }
}

// ---------------------------------------------------------------------------
// flash_kernel: per (b, 64-row q-tile): online-softmax attention over N=4096.
//   S = Q K'^T via split-bf16 3-term MFMA (~fp32), P bf16, O^T = V P^T
//   out[b][c][n] = gamma * O^T[c][n] / l[n] + x[b][c][n]
// ---------------------------------------------------------------------------
__global__ __launch_bounds__(256) void flash_kernel(
    const float* __restrict__ Qf,
    const float* __restrict__ Kf,
    const unsigned short* __restrict__ Vg,
    const float* __restrict__ x,
    const float* __restrict__ gamma,
    float* __restrict__ out)
{
    __shared__ unsigned short KVh[256 * 72];   // K' hi view [64][264]; V view [256][72]
    __shared__ unsigned short Klo[64 * 264];   // K' lo [64][264]
    __shared__ unsigned short Pt[4 * 64 * 20]; // per-wave P^T [j][m], pitch 20
    __shared__ float abuf[4][16];              // per-wave alpha / l broadcast

    const int t    = threadIdx.x;
    const int wave = t >> 6;
    const int lane = t & 63;
    const int l15  = lane & 15;
    const int quad = lane >> 4;

    const int bid = blockIdx.x;
    const int b   = bid & 3;                              // XCD-swizzle: same-b blocks share an XCD's L2
    const int qt  = ((bid >> 3) << 1) | ((bid >> 2) & 1); // 0..63

    const float* Qb = Qf + (size_t)b * N_TOK * C_DIM;
    const float* Kb = Kf + (size_t)b * N_TOK * C_DIM;
    const unsigned short* Vb = Vg + (size_t)b * C_DIM * N_TOK;

    // Q fragments resident in registers, split hi/lo: 16 rows x 256 c per wave
    short8 qh[8], ql[8];
    const int qrow = qt * 64 + wave * 16 + l15;
    {
        const float* Qrow = Qb + (size_t)qrow * C_DIM;
#pragma unroll
        for (int ct = 0; ct < 8; ct++) {
            const int base = ct * 32 + quad * 8;
            const float4 f0 = *(const float4*)&Qrow[base];
            const float4 f1 = *(const float4*)&Qrow[base + 4];
            short8 hh, ll;
            unsigned short h, l;
            split_bf16(f0.x, h, l); hh[0] = (short)h; ll[0] = (short)l;
            split_bf16(f0.y, h, l); hh[1] = (short)h; ll[1] = (short)l;
            split_bf16(f0.z, h, l); hh[2] = (short)h; ll[2] = (short)l;
            split_bf16(f0.w, h, l); hh[3] = (short)h; ll[3] = (short)l;
            split_bf16(f1.x, h, l); hh[4] = (short)h; ll[4] = (short)l;
            split_bf16(f1.y, h, l); hh[5] = (short)h; ll[5] = (short)l;
            split_bf16(f1.z, h, l); hh[6] = (short)h; ll[6] = (short)l;
            split_bf16(f1.w, h, l); hh[7] = (short)h; ll[7] = (short)l;
            qh[ct] = hh; ql[ct] = ll;
        }
    }

    floatx4 oacc[16];
#pragma unroll
    for (int i = 0; i < 16; i++) oacc[i] = (floatx4){0.f, 0.f, 0.f, 0.f};
    float m_i[4] = {-1e30f, -1e30f, -1e30f, -1e30f};
    float l_i[4] = {0.f, 0.f, 0.f, 0.f};

    unsigned short* Ptw = Pt + wave * 64 * 20;

    for (int j0 = 0; j0 < N_TOK; j0 += 64) {
        // ---- stage K' tile fp32 -> split bf16 [64][264] hi + lo
        {
            const int ch = t & 31;     // 8-channel chunk
            const int jr = t >> 5;     // 8 rows per pass
#pragma unroll
            for (int pass = 0; pass < 8; pass++) {
                const int j = pass * 8 + jr;
                const float* src = Kb + (size_t)(j0 + j) * C_DIM + ch * 8;
                const float4 f0 = *(const float4*)src;
                const float4 f1 = *(const float4*)(src + 4);
                short8 hh, ll;
                unsigned short h, l;
                split_bf16(f0.x, h, l); hh[0] = (short)h; ll[0] = (short)l;
                split_bf16(f0.y, h, l); hh[1] = (short)h; ll[1] = (short)l;
                split_bf16(f0.z, h, l); hh[2] = (short)h; ll[2] = (short)l;
                split_bf16(f0.w, h, l); hh[3] = (short)h; ll[3] = (short)l;
                split_bf16(f1.x, h, l); hh[4] = (short)h; ll[4] = (short)l;
                split_bf16(f1.y, h, l); hh[5] = (short)h; ll[5] = (short)l;
                split_bf16(f1.z, h, l); hh[6] = (short)h; ll[6] = (short)l;
                split_bf16(f1.w, h, l); hh[7] = (short)h; ll[7] = (short)l;
                *(short8*)&KVh[j * 264 + ch * 8] = hh;
                *(short8*)&Klo[j * 264 + ch * 8] = ll;
            }
        }
        __syncthreads();

        // ---- S = Q K'^T  (3-term split; C layout: row m = quad*4+r, col j = l15)
        floatx4 s[4];
#pragma unroll
        for (int jt = 0; jt < 4; jt++) {
            floatx4 a = (floatx4){0.f, 0.f, 0.f, 0.f};
#pragma unroll
            for (int ct = 0; ct < 8; ct++) {
                const int krow = (jt * 16 + l15) * 264 + ct * 32 + quad * 8;
                const short8 kh = *(const short8*)&KVh[krow];
                const short8 kl = *(const short8*)&Klo[krow];
                a = __builtin_amdgcn_mfma_f32_16x16x32_bf16(qh[ct], kh, a, 0, 0, 0);
                a = __builtin_amdgcn_mfma_f32_16x16x32_bf16(ql[ct], kh, a, 0, 0, 0);
                a = __builtin_amdgcn_mfma_f32_16x16x32_bf16(qh[ct], kl, a, 0, 0, 0);
            }
            s[jt] = a;
        }

        // ---- online softmax (reduce over 16 lanes of each quad-row-group)
        float alpha[4];
#pragma unroll
        for (int r = 0; r < 4; r++) {
            float mx = fmaxf(fmaxf(s[0][r], s[1][r]), fmaxf(s[2][r], s[3][r]));
            mx = fmaxf(mx, __shfl_xor(mx, 1));
            mx = fmaxf(mx, __shfl_xor(mx, 2));
            mx = fmaxf(mx, __shfl_xor(mx, 4));
            mx = fmaxf(mx, __shfl_xor(mx, 8));
            const float mn = fmaxf(m_i[r], mx);
            alpha[r] = __expf(m_i[r] - mn);
            m_i[r] = mn;
            float ps = 0.f;
#pragma unroll
            for (int jt = 0; jt < 4; jt++) {
                const float p = __expf(s[jt][r] - mn);
                s[jt][r] = p;
                ps += p;
            }
            ps += __shfl_xor(ps, 1);
            ps += __shfl_xor(ps, 2);
            ps += __shfl_xor(ps, 4);
            ps += __shfl_xor(ps, 8);
            l_i[r] = l_i[r] * alpha[r] + ps;
        }
        if (l15 == 0)
            *(float4*)&abuf[wave][quad * 4] = make_float4(alpha[0], alpha[1], alpha[2], alpha[3]);

        // ---- write P^T [j][m] (bf16)
#pragma unroll
        for (int jt = 0; jt < 4; jt++) {
            const unsigned int u0 = (unsigned int)bf16_rne(s[jt][0]) | ((unsigned int)bf16_rne(s[jt][1]) << 16);
            const unsigned int u1 = (unsigned int)bf16_rne(s[jt][2]) | ((unsigned int)bf16_rne(s[jt][3]) << 16);
            uint2 uv; uv.x = u0; uv.y = u1;
            *(uint2*)&Ptw[(jt * 16 + l15) * 20 + quad * 4] = uv;
        }
        __syncthreads();   // K' consumed; alpha + P^T visible

        // ---- rescale O by alpha
        const float am = abuf[wave][l15];
#pragma unroll
        for (int ot = 0; ot < 16; ot++) {
            oacc[ot][0] *= am; oacc[ot][1] *= am; oacc[ot][2] *= am; oacc[ot][3] *= am;
        }

        // ---- stage V tile [256][72] (channel-major, overwrites K' hi region)
        {
            const int ch   = t & 7;
            const int orow = t >> 3;
#pragma unroll
            for (int pass = 0; pass < 8; pass++) {
                const int o = pass * 32 + orow;
                const short8 vv = *(const short8*)&Vb[(size_t)o * N_TOK + j0 + ch * 8];
                *(short8*)&KVh[o * 72 + ch * 8] = vv;
            }
        }
        __syncthreads();

        // ---- O^T += V P^T
        short8 pf[2];
#pragma unroll
        for (int k0 = 0; k0 < 2; k0++) {
            short8 p;
#pragma unroll
            for (int jj = 0; jj < 8; jj++)
                p[jj] = (short)Ptw[(k0 * 32 + quad * 8 + jj) * 20 + l15];
            pf[k0] = p;
        }
#pragma unroll
        for (int ot = 0; ot < 16; ot++) {
            const int vrow = (ot * 16 + l15) * 72 + quad * 8;
            const short8 av0 = *(const short8*)&KVh[vrow];
            const short8 av1 = *(const short8*)&KVh[vrow + 32];
            oacc[ot] = __builtin_amdgcn_mfma_f32_16x16x32_bf16(av0, pf[0], oacc[ot], 0, 0, 0);
            oacc[ot] = __builtin_amdgcn_mfma_f32_16x16x32_bf16(av1, pf[1], oacc[ot], 0, 0, 0);
        }
        __syncthreads();   // protect KVh/Pt before next tile
    }

    // ---- epilogue: out = gamma * O^T / l + x
    if (l15 == 0)
        *(float4*)&abuf[wave][quad * 4] = make_float4(l_i[0], l_i[1], l_i[2], l_i[3]);
    __syncthreads();
    const float linv = 1.0f / abuf[wave][l15];
    const float g = gamma[0];
    const int n = qt * 64 + wave * 16 + l15;
#pragma unroll
    for (int ot = 0; ot < 16; ot++) {
#pragma unroll
        for (int r = 0; r < 4; r++) {
            const int c = ot * 16 + quad * 4 + r;
            const size_t idx = ((size_t)b * C_DIM + c) * N_TOK + n;
            out[idx] = g * oacc[ot][r] * linv + x[idx];
        }
    }
}

extern "C" void kernel_launch(void* const* d_in, const int* in_sizes, int n_in,
                              void* d_out, int out_size, void* d_ws, size_t ws_size,
                              hipStream_t stream) {
    const float* x     = (const float*)d_in[0];
    const float* Wq    = (const float*)d_in[1];
    const float* bq    = (const float*)d_in[2];
    const float* Wk    = (const float*)d_in[3];
    const float* bk    = (const float*)d_in[4];
    const float* Wv    = (const float*)d_in[5];
    const float* bv    = (const float*)d_in[6];
    const float* relh  = (const float*)d_in[7];
    const float* relw  = (const float*)d_in[8];
    const float* gamma = (const float*)d_in[9];
    float* out = (float*)d_out;

    float* Qf = (float*)d_ws;                                   // [4][4096][256] fp32
    float* Kf = Qf + (size_t)4 * N_TOK * C_DIM;                 // [4][4096][256] fp32 (k + pos)
    unsigned short* Vg = (unsigned short*)(Kf + (size_t)4 * N_TOK * C_DIM); // [4][256][4096] bf16

    hipLaunchKernelGGL(proj_kernel, dim3(768), dim3(256), 0, stream,
                       x, Wq, bq, Wk, bk, Wv, bv, relh, relw, Qf, Kf, Vg);
    hipLaunchKernelGGL(flash_kernel, dim3(256), dim3(256), 0, stream,
                       Qf, Kf, Vg, x, gamma, out);
}

// Round 3
// 336.600 us; speedup vs baseline: 1.4861x; 1.4861x over previous
//
#include <hip/hip_runtime.h>
#include <stdint.h>

#define N_TOK 4096
#define C_DIM 256

typedef __attribute__((ext_vector_type(8))) short short8;
typedef __attribute__((ext_vector_type(4))) float floatx4;

__device__ __forceinline__ unsigned short bf16_rne(float f) {
    union { float f; unsigned int u; } v; v.f = f;
    unsigned int u = v.u;
    unsigned int rounded = u + 0x7FFFu + ((u >> 16) & 1u);
    return (unsigned short)(rounded >> 16);
}
__device__ __forceinline__ float bf16_to_f(unsigned short h) {
    union { unsigned int u; float f; } v; v.u = ((unsigned int)h) << 16;
    return v.f;
}
// split f = hi + lo (both bf16) with combined error ~2^-18 relative
__device__ __forceinline__ void split_bf16(float f, unsigned short& h, unsigned short& l) {
    h = bf16_rne(f);
    l = bf16_rne(f - bf16_to_f(h));
}
// async global->LDS 16B/lane; LDS dest = wave-uniform base + lane*16
__device__ __forceinline__ void g2l16(const void* g, void* l) {
    __builtin_amdgcn_global_load_lds(
        (const __attribute__((address_space(1))) void*)g,
        (__attribute__((address_space(3))) void*)l, 16, 0, 0);
}

// ---------------------------------------------------------------------------
// proj_kernel: Out[n,o] = sum_c x[b,c,n]*W[o,c] + bias[o] (+pos[o,n] for k)
// Split-bf16 3-term MFMA for ~fp32 accuracy. Outputs:
//   Qf[b][n][o] fp32, Khi/Klo[b][n][o] bf16 split (K' = k + pos), Vg[b][o][n] bf16
// ---------------------------------------------------------------------------
__global__ __launch_bounds__(256) void proj_kernel(
    const float* __restrict__ x,
    const float* __restrict__ Wq, const float* __restrict__ bq,
    const float* __restrict__ Wk, const float* __restrict__ bk,
    const float* __restrict__ Wv, const float* __restrict__ bv,
    const float* __restrict__ relh, const float* __restrict__ relw,
    float* __restrict__ Qf,
    unsigned short* __restrict__ Khi,
    unsigned short* __restrict__ Klo,
    unsigned short* __restrict__ Vg)
{
    __shared__ unsigned short Xh[64 * 72];    // x tile hi [n_loc][c_loc]
    __shared__ unsigned short Xl[64 * 72];    // x tile lo
    __shared__ unsigned short Wh[256 * 72];   // W tile hi [o][c_loc]; reused for V transpose
    __shared__ unsigned short Wl[256 * 72];   // W tile lo

    const int t    = threadIdx.x;
    const int wave = t >> 6;
    const int lane = t & 63;
    const int l15  = lane & 15;
    const int quad = lane >> 4;

    const int bp   = blockIdx.x >> 6;       // 0..11
    const int proj = bp % 3;
    const int b    = bp / 3;
    const int n0   = (blockIdx.x & 63) * 64;

    const float* W    = (proj == 0) ? Wq : (proj == 1) ? Wk : Wv;
    const float* bias = (proj == 0) ? bq : (proj == 1) ? bk : bv;

    floatx4 acc[16];
#pragma unroll
    for (int i = 0; i < 16; i++) acc[i] = (floatx4){0.f, 0.f, 0.f, 0.f};

    for (int c0 = 0; c0 < 256; c0 += 64) {
        // ---- stage x tile transposed + split: Xh/Xl[n_loc][c_loc]
        {
            const int ch   = t & 15;     // float4 chunk along n
            const int crow = t >> 4;     // 0..15
#pragma unroll
            for (int pass = 0; pass < 4; pass++) {
                const int c_loc = pass * 16 + crow;
                const float4 xv = *(const float4*)(x + ((size_t)(b * C_DIM + c0 + c_loc)) * N_TOK + n0 + ch * 4);
                const int nb = ch * 4;
                unsigned short h, l;
                split_bf16(xv.x, h, l); Xh[(nb + 0) * 72 + c_loc] = h; Xl[(nb + 0) * 72 + c_loc] = l;
                split_bf16(xv.y, h, l); Xh[(nb + 1) * 72 + c_loc] = h; Xl[(nb + 1) * 72 + c_loc] = l;
                split_bf16(xv.z, h, l); Xh[(nb + 2) * 72 + c_loc] = h; Xl[(nb + 2) * 72 + c_loc] = l;
                split_bf16(xv.w, h, l); Xh[(nb + 3) * 72 + c_loc] = h; Xl[(nb + 3) * 72 + c_loc] = l;
            }
        }
        // ---- stage W tile split: Wh/Wl[o][c_loc]
        {
            const int ch   = t & 7;
            const int orow = t >> 3;     // 0..31
#pragma unroll
            for (int pass = 0; pass < 8; pass++) {
                const int o = pass * 32 + orow;
                const float* src = W + (size_t)o * 256 + c0 + ch * 8;
                const float4 w0 = *(const float4*)src;
                const float4 w1 = *(const float4*)(src + 4);
                short8 wh, wl;
                unsigned short h, l;
                split_bf16(w0.x, h, l); wh[0] = (short)h; wl[0] = (short)l;
                split_bf16(w0.y, h, l); wh[1] = (short)h; wl[1] = (short)l;
                split_bf16(w0.z, h, l); wh[2] = (short)h; wl[2] = (short)l;
                split_bf16(w0.w, h, l); wh[3] = (short)h; wl[3] = (short)l;
                split_bf16(w1.x, h, l); wh[4] = (short)h; wl[4] = (short)l;
                split_bf16(w1.y, h, l); wh[5] = (short)h; wl[5] = (short)l;
                split_bf16(w1.z, h, l); wh[6] = (short)h; wl[6] = (short)l;
                split_bf16(w1.w, h, l); wh[7] = (short)h; wl[7] = (short)l;
                *(short8*)&Wh[o * 72 + ch * 8] = wh;
                *(short8*)&Wl[o * 72 + ch * 8] = wl;
            }
        }
        __syncthreads();

        const int arow = (wave * 16 + l15) * 72 + quad * 8;
        const short8 a0h = *(const short8*)&Xh[arow];
        const short8 a0l = *(const short8*)&Xl[arow];
        const short8 a1h = *(const short8*)&Xh[arow + 32];
        const short8 a1l = *(const short8*)&Xl[arow + 32];
#pragma unroll
        for (int ot = 0; ot < 16; ot++) {
            const int brow = (ot * 16 + l15) * 72 + quad * 8;
            const short8 b0h = *(const short8*)&Wh[brow];
            const short8 b0l = *(const short8*)&Wl[brow];
            const short8 b1h = *(const short8*)&Wh[brow + 32];
            const short8 b1l = *(const short8*)&Wl[brow + 32];
            acc[ot] = __builtin_amdgcn_mfma_f32_16x16x32_bf16(a0h, b0h, acc[ot], 0, 0, 0);
            acc[ot] = __builtin_amdgcn_mfma_f32_16x16x32_bf16(a0l, b0h, acc[ot], 0, 0, 0);
            acc[ot] = __builtin_amdgcn_mfma_f32_16x16x32_bf16(a0h, b0l, acc[ot], 0, 0, 0);
            acc[ot] = __builtin_amdgcn_mfma_f32_16x16x32_bf16(a1h, b1h, acc[ot], 0, 0, 0);
            acc[ot] = __builtin_amdgcn_mfma_f32_16x16x32_bf16(a1l, b1h, acc[ot], 0, 0, 0);
            acc[ot] = __builtin_amdgcn_mfma_f32_16x16x32_bf16(a1h, b1l, acc[ot], 0, 0, 0);
        }
        __syncthreads();
    }

    // ---- epilogue ----
    const int h0 = n0 >> 6;   // pos[c][n] = relh[c][n>>6] + relw[c][n&63]
    if (proj == 0) {
        float* Og = Qf + ((size_t)b * N_TOK + n0) * C_DIM;
#pragma unroll
        for (int ot = 0; ot < 16; ot++) {
            const int o = ot * 16 + l15;
            const float bs = bias[o];
#pragma unroll
            for (int r = 0; r < 4; r++) {
                const int nl = wave * 16 + quad * 4 + r;
                Og[(size_t)nl * C_DIM + o] = acc[ot][r] + bs;
            }
        }
    } else if (proj == 1) {
        unsigned short* Oh = Khi + ((size_t)b * N_TOK + n0) * C_DIM;
        unsigned short* Ol = Klo + ((size_t)b * N_TOK + n0) * C_DIM;
#pragma unroll
        for (int ot = 0; ot < 16; ot++) {
            const int o = ot * 16 + l15;
            const float bs = bias[o];
            const float ph = relh[o * 64 + h0];
#pragma unroll
            for (int r = 0; r < 4; r++) {
                const int nl = wave * 16 + quad * 4 + r;
                const float val = acc[ot][r] + bs + ph + relw[o * 64 + nl];
                unsigned short h, l;
                split_bf16(val, h, l);
                Oh[(size_t)nl * C_DIM + o] = h;
                Ol[(size_t)nl * C_DIM + o] = l;
            }
        }
    } else {
        // V: bf16, transpose via LDS (reuse Wh) -> Vg[b][o][n]
#pragma unroll
        for (int ot = 0; ot < 16; ot++) {
            const int o = ot * 16 + l15;
            const float bs = bias[o];
            const unsigned int u0 = (unsigned int)bf16_rne(acc[ot][0] + bs) |
                                    ((unsigned int)bf16_rne(acc[ot][1] + bs) << 16);
            const unsigned int u1 = (unsigned int)bf16_rne(acc[ot][2] + bs) |
                                    ((unsigned int)bf16_rne(acc[ot][3] + bs) << 16);
            uint2 uv; uv.x = u0; uv.y = u1;
            *(uint2*)&Wh[o * 72 + wave * 16 + quad * 4] = uv;
        }
        __syncthreads();
        const int ch   = t & 7;
        const int orow = t >> 3;
#pragma unroll
        for (int pass = 0; pass < 8; pass++) {
            const int o = pass * 32 + orow;
            const short8 vv = *(const short8*)&Wh[o * 72 + ch * 8];
            *(short8*)&Vg[((size_t)b * C_DIM + o) * N_TOK + n0 + ch * 8] = vv;
        }
    }
}

// ---------------------------------------------------------------------------
// flash_kernel (split-K x2): block handles (b, s=half of j-range, 64-row q-tile).
// K/V staged via global_load_lds with XOR-chunk-swizzled LDS (conflict-free,
// no padding). P^T stored [m][j] so the PV B-fragment is one ds_read_b128.
// Writes unnormalized O^T (bf16) + per-row (m,l) for the merge kernel.
// ---------------------------------------------------------------------------
__global__ __launch_bounds__(256, 2) void flash_kernel(
    const float* __restrict__ Qf,
    const unsigned short* __restrict__ Khi,
    const unsigned short* __restrict__ Klo,
    const unsigned short* __restrict__ Vg,
    unsigned short* __restrict__ Op,   // [2][4][256][4096] bf16, unnormalized
    float* __restrict__ Lm)            // [2][4][4096] float2 (m,l)
{
    __shared__ unsigned short KhiS[64 * 256];  // 32KB; reused as V [256][64] view
    __shared__ unsigned short KloS[64 * 256];  // 32KB
    __shared__ unsigned short Pt[4 * 16 * 72]; // per-wave P^T [m][j], pitch 72
    __shared__ float abuf[4][16];
    unsigned short* Vs = KhiS;                 // [o][j] pitch 64, chunk-swizzled

    const int t    = threadIdx.x;
    const int wave = t >> 6;
    const int lane = t & 63;
    const int l15  = lane & 15;
    const int quad = lane >> 4;
    const int lk   = l15 & 7;   // swizzle key

    const int bid = blockIdx.x;
    const int b   = bid & 3;          // bid%8 <-> (b,s): each XCD owns one K/V half
    const int s   = (bid >> 2) & 1;
    const int qt  = bid >> 3;         // 0..63

    const float* Qb = Qf + (size_t)b * N_TOK * C_DIM;
    const unsigned short* Khb = Khi + (size_t)b * N_TOK * C_DIM;
    const unsigned short* Klb = Klo + (size_t)b * N_TOK * C_DIM;
    const unsigned short* Vb  = Vg  + (size_t)b * C_DIM * N_TOK;

    // Q fragments resident in registers, split hi/lo: 16 rows x 256 c per wave
    short8 qh[8], ql[8];
    const int qrow = qt * 64 + wave * 16 + l15;
    {
        const float* Qrow = Qb + (size_t)qrow * C_DIM;
#pragma unroll
        for (int ct = 0; ct < 8; ct++) {
            const int base = ct * 32 + quad * 8;
            const float4 f0 = *(const float4*)&Qrow[base];
            const float4 f1 = *(const float4*)&Qrow[base + 4];
            short8 hh, ll;
            unsigned short h, l;
            split_bf16(f0.x, h, l); hh[0] = (short)h; ll[0] = (short)l;
            split_bf16(f0.y, h, l); hh[1] = (short)h; ll[1] = (short)l;
            split_bf16(f0.z, h, l); hh[2] = (short)h; ll[2] = (short)l;
            split_bf16(f0.w, h, l); hh[3] = (short)h; ll[3] = (short)l;
            split_bf16(f1.x, h, l); hh[4] = (short)h; ll[4] = (short)l;
            split_bf16(f1.y, h, l); hh[5] = (short)h; ll[5] = (short)l;
            split_bf16(f1.z, h, l); hh[6] = (short)h; ll[6] = (short)l;
            split_bf16(f1.w, h, l); hh[7] = (short)h; ll[7] = (short)l;
            qh[ct] = hh; ql[ct] = ll;
        }
    }

    floatx4 oacc[16];
#pragma unroll
    for (int i = 0; i < 16; i++) oacc[i] = (floatx4){0.f, 0.f, 0.f, 0.f};
    float m_i[4] = {-1e30f, -1e30f, -1e30f, -1e30f};
    float l_i[4] = {0.f, 0.f, 0.f, 0.f};

    unsigned short* Ptw = Pt + wave * 16 * 72;
    const int jbase = s * 2048;

    for (int ti = 0; ti < 32; ti++) {
        const int j0 = jbase + ti * 64;

        // ---- stage K' hi+lo via async DMA; LDS chunk c' holds global chunk c'^(row&7)
        {
            const int lr = lane >> 5;     // 0/1: row within 2-row block
            const int cp = lane & 31;     // chunk within row (32 x 16B)
#pragma unroll
            for (int p = 0; p < 8; p++) {
                const int jl = wave * 16 + p * 2 + lr;
                const int g  = cp ^ (jl & 7);
                const size_t go = (size_t)(j0 + jl) * C_DIM + g * 8;
                g2l16(Khb + go, &KhiS[(wave * 16 + p * 2) * 256]);
                g2l16(Klb + go, &KloS[(wave * 16 + p * 2) * 256]);
            }
        }
        __syncthreads();

        // ---- S = Q K'^T (3-term split)
        floatx4 sv[4];
#pragma unroll
        for (int jt = 0; jt < 4; jt++) {
            floatx4 a = (floatx4){0.f, 0.f, 0.f, 0.f};
#pragma unroll
            for (int ct = 0; ct < 8; ct++) {
                const int cidx = (ct * 4 + quad) ^ lk;
                const int off = (jt * 16 + l15) * 256 + cidx * 8;
                const short8 kh = *(const short8*)&KhiS[off];
                const short8 kl = *(const short8*)&KloS[off];
                a = __builtin_amdgcn_mfma_f32_16x16x32_bf16(qh[ct], kh, a, 0, 0, 0);
                a = __builtin_amdgcn_mfma_f32_16x16x32_bf16(ql[ct], kh, a, 0, 0, 0);
                a = __builtin_amdgcn_mfma_f32_16x16x32_bf16(qh[ct], kl, a, 0, 0, 0);
            }
            sv[jt] = a;
        }

        // ---- online softmax
        float alpha[4];
#pragma unroll
        for (int r = 0; r < 4; r++) {
            float mx = fmaxf(fmaxf(sv[0][r], sv[1][r]), fmaxf(sv[2][r], sv[3][r]));
            mx = fmaxf(mx, __shfl_xor(mx, 1));
            mx = fmaxf(mx, __shfl_xor(mx, 2));
            mx = fmaxf(mx, __shfl_xor(mx, 4));
            mx = fmaxf(mx, __shfl_xor(mx, 8));
            const float mn = fmaxf(m_i[r], mx);
            alpha[r] = __expf(m_i[r] - mn);
            m_i[r] = mn;
            float ps = 0.f;
#pragma unroll
            for (int jt = 0; jt < 4; jt++) {
                const float p = __expf(sv[jt][r] - mn);
                sv[jt][r] = p;
                ps += p;
            }
            ps += __shfl_xor(ps, 1);
            ps += __shfl_xor(ps, 2);
            ps += __shfl_xor(ps, 4);
            ps += __shfl_xor(ps, 8);
            l_i[r] = l_i[r] * alpha[r] + ps;
        }
        if (l15 == 0)
            *(float4*)&abuf[wave][quad * 4] = make_float4(alpha[0], alpha[1], alpha[2], alpha[3]);

        // ---- write P^T [m][j] (16 u16 stores, 2-way max)
#pragma unroll
        for (int jt = 0; jt < 4; jt++) {
#pragma unroll
            for (int r = 0; r < 4; r++)
                Ptw[(quad * 4 + r) * 72 + jt * 16 + l15] = bf16_rne(sv[jt][r]);
        }
        __syncthreads();   // K' fully consumed; alpha + P^T visible

        // ---- B-fragments from P^T (b128), V staging (async), O rescale
        const short8 pf0 = *(const short8*)&Ptw[l15 * 72 + quad * 8];
        const short8 pf1 = *(const short8*)&Ptw[l15 * 72 + 32 + quad * 8];
        {
            const int lr = lane >> 3;     // 0..7: row within 8-row block
            const int cp = lane & 7;      // chunk within row (8 x 16B)
#pragma unroll
            for (int p = 0; p < 8; p++) {
                const int ob = (p * 4 + wave) * 8;
                const int o  = ob + lr;
                const int g  = cp ^ (o & 7);
                g2l16(Vb + (size_t)o * N_TOK + j0 + g * 8, &Vs[ob * 64]);
            }
        }
        const float am = abuf[wave][l15];
#pragma unroll
        for (int ot = 0; ot < 16; ot++) {
            oacc[ot][0] *= am; oacc[ot][1] *= am; oacc[ot][2] *= am; oacc[ot][3] *= am;
        }
        __syncthreads();   // V visible

        // ---- O^T += V P^T
#pragma unroll
        for (int ot = 0; ot < 16; ot++) {
            const int row = (ot * 16 + l15) * 64;
            const short8 av0 = *(const short8*)&Vs[row + (quad ^ lk) * 8];
            const short8 av1 = *(const short8*)&Vs[row + ((4 + quad) ^ lk) * 8];
            oacc[ot] = __builtin_amdgcn_mfma_f32_16x16x32_bf16(av0, pf0, oacc[ot], 0, 0, 0);
            oacc[ot] = __builtin_amdgcn_mfma_f32_16x16x32_bf16(av1, pf1, oacc[ot], 0, 0, 0);
        }
        __syncthreads();   // protect Vs/KloS before next tile staging
    }

    // ---- epilogue: unnormalized O^T (bf16) + (m,l)
    unsigned short* Ob = Op + ((size_t)(s * 4 + b) * C_DIM) * N_TOK;
    const int n = qt * 64 + wave * 16 + l15;
#pragma unroll
    for (int ot = 0; ot < 16; ot++) {
#pragma unroll
        for (int r = 0; r < 4; r++) {
            const int c = ot * 16 + quad * 4 + r;
            Ob[(size_t)c * N_TOK + n] = bf16_rne(oacc[ot][r]);
        }
    }
    if (l15 == 0) {
        const size_t nb = (size_t)(s * 4 + b) * N_TOK + qt * 64 + wave * 16 + quad * 4;
#pragma unroll
        for (int r = 0; r < 4; r++)
            *(float2*)&Lm[(nb + r) * 2] = make_float2(m_i[r], l_i[r]);
    }
}

// ---------------------------------------------------------------------------
// merge_kernel: out[b][c][n] = gamma*(w0*O0+w1*O1)/(w0*l0+w1*l1) + x
// ---------------------------------------------------------------------------
__global__ __launch_bounds__(256) void merge_kernel(
    const unsigned short* __restrict__ Op,
    const float* __restrict__ Lm,
    const float* __restrict__ x,
    const float* __restrict__ gamma,
    float* __restrict__ out)
{
    const int blk = blockIdx.x;          // 4096
    const int b   = blk >> 10;
    const int c   = (blk >> 2) & 255;
    const int nq  = blk & 3;
    const int n0  = nq * 1024 + threadIdx.x * 4;

    const size_t half = (size_t)4 * C_DIM * N_TOK;
    const size_t obase = ((size_t)b * C_DIM + c) * N_TOK + n0;
    const uint2 u0 = *(const uint2*)&Op[obase];
    const uint2 u1 = *(const uint2*)&Op[half + obase];

    const float* Lm0 = Lm + (size_t)b * N_TOK * 2;
    const float* Lm1 = Lm + (size_t)(4 + b) * N_TOK * 2;
    const float4 A0 = *(const float4*)&Lm0[n0 * 2];
    const float4 A1 = *(const float4*)&Lm0[n0 * 2 + 4];
    const float4 B0 = *(const float4*)&Lm1[n0 * 2];
    const float4 B1 = *(const float4*)&Lm1[n0 * 2 + 4];
    const float4 xv = *(const float4*)&x[obase];
    const float g = gamma[0];

    const float m0[4] = {A0.x, A0.z, A1.x, A1.z};
    const float l0[4] = {A0.y, A0.w, A1.y, A1.w};
    const float m1[4] = {B0.x, B0.z, B1.x, B1.z};
    const float l1[4] = {B0.y, B0.w, B1.y, B1.w};
    const float o0[4] = {bf16_to_f((unsigned short)(u0.x & 0xffff)),
                         bf16_to_f((unsigned short)(u0.x >> 16)),
                         bf16_to_f((unsigned short)(u0.y & 0xffff)),
                         bf16_to_f((unsigned short)(u0.y >> 16))};
    const float o1[4] = {bf16_to_f((unsigned short)(u1.x & 0xffff)),
                         bf16_to_f((unsigned short)(u1.x >> 16)),
                         bf16_to_f((unsigned short)(u1.y & 0xffff)),
                         bf16_to_f((unsigned short)(u1.y >> 16))};
    const float xin[4] = {xv.x, xv.y, xv.z, xv.w};

    float4 res;
    float* rp = (float*)&res;
#pragma unroll
    for (int i = 0; i < 4; i++) {
        const float M  = fmaxf(m0[i], m1[i]);
        const float w0 = __expf(m0[i] - M);
        const float w1 = __expf(m1[i] - M);
        const float lsum = w0 * l0[i] + w1 * l1[i];
        rp[i] = g * (w0 * o0[i] + w1 * o1[i]) / lsum + xin[i];
    }
    *(float4*)&out[obase] = res;
}

extern "C" void kernel_launch(void* const* d_in, const int* in_sizes, int n_in,
                              void* d_out, int out_size, void* d_ws, size_t ws_size,
                              hipStream_t stream) {
    const float* x     = (const float*)d_in[0];
    const float* Wq    = (const float*)d_in[1];
    const float* bq    = (const float*)d_in[2];
    const float* Wk    = (const float*)d_in[3];
    const float* bk    = (const float*)d_in[4];
    const float* Wv    = (const float*)d_in[5];
    const float* bv    = (const float*)d_in[6];
    const float* relh  = (const float*)d_in[7];
    const float* relw  = (const float*)d_in[8];
    const float* gamma = (const float*)d_in[9];
    float* out = (float*)d_out;

    const size_t NE = (size_t)4 * N_TOK * C_DIM;   // 4.19M elems
    float* Qf = (float*)d_ws;                      // fp32 [4][4096][256]
    unsigned short* Khi = (unsigned short*)(Qf + NE);
    unsigned short* Klo = Khi + NE;
    unsigned short* Vg  = Klo + NE;                // bf16 [4][256][4096]
    unsigned short* Op  = Vg + NE;                 // bf16 [2][4][256][4096]
    float* Lm = (float*)(Op + 2 * NE);             // float2 [2][4][4096]

    hipLaunchKernelGGL(proj_kernel, dim3(768), dim3(256), 0, stream,
                       x, Wq, bq, Wk, bk, Wv, bv, relh, relw, Qf, Khi, Klo, Vg);
    hipLaunchKernelGGL(flash_kernel, dim3(512), dim3(256), 0, stream,
                       Qf, Khi, Klo, Vg, Op, Lm);
    hipLaunchKernelGGL(merge_kernel, dim3(4096), dim3(256), 0, stream,
                       Op, Lm, x, gamma, out);
}